// Round 10
// baseline (393.927 us; speedup 1.0000x reference)
//
#include <hip/hip_runtime.h>
#include <hip/hip_bf16.h>

typedef __hip_bfloat16 bf16;
typedef __attribute__((ext_vector_type(8))) __bf16 bf16x8;
typedef __attribute__((ext_vector_type(4))) float f32x4;

__device__ __forceinline__ float toF(bf16 v) { return __bfloat162float(v); }

// dual-dtype load: dt=1 -> underlying memory is fp32; dt=0 -> bf16
__device__ __forceinline__ float ldf(const void* p, size_t i, int dt) {
  return dt ? ((const float*)p)[i] : __bfloat162float(((const bf16*)p)[i]);
}
__device__ __forceinline__ ushort toBF(float f) {
  union { bf16 b; ushort u; } cv; cv.b = __float2bfloat16(f); return cv.u;
}

// ---------------- dtype detection ----------------
__global__ void detect_dtype(const void* x, int n, int* flag) {
  __shared__ int s;
  if (threadIdx.x == 0) s = 0;
  __syncthreads();
  const bf16* xb = (const bf16*)x;
  int bad = 0;
  for (int i = threadIdx.x; i < n; i += 256) {
    float v = __bfloat162float(xb[i]);
    if (!(fabsf(v) < 1e6f)) bad = 1;
  }
  if (bad) atomicOr(&s, 1);
  __syncthreads();
  if (threadIdx.x == 0) flag[0] = s;
}

// ---------------- optional x -> bf16 repack (only runs when dt==1) ----------------
__global__ void pack_xp(const void* __restrict__ x, ushort* __restrict__ xp, size_t total,
                        const int* __restrict__ dtflag) {
  if (dtflag[0] == 0) return;
  const float* xf = (const float*)x;
  size_t stride = (size_t)gridDim.x * blockDim.x;
  for (size_t i = blockIdx.x * (size_t)blockDim.x + threadIdx.x; i < total; i += stride)
    xp[i] = toBF(xf[i]);
}

// ---------------- CSR build (real edges only; self-loops analytic in agg) -------------
__global__ void count_rank(const int* __restrict__ ei, int E,
                           int* __restrict__ cnt, int* __restrict__ rank) {
  int e = blockIdx.x * blockDim.x + threadIdx.x;
  if (e >= E) return;
  int d = ei[E + e];
  rank[e] = atomicAdd(&cnt[d], 1);
}

// single block, 1024 threads: exclusive scan of cnt[0..n) -> rowstart; rowstart[n]=total
__global__ void scan1(const int* __restrict__ cnt, int* __restrict__ rowstart, int n) {
  __shared__ int wsum[16];
  __shared__ int carry_s;
  int t = threadIdx.x, lane = t & 63, w = t >> 6;
  if (t == 0) carry_s = 0;
  __syncthreads();
  for (int base = 0; base < n; base += 1024) {
    int i = base + t;
    int v = (i < n) ? cnt[i] : 0;
    int x = v;
#pragma unroll
    for (int off = 1; off < 64; off <<= 1) {
      int y = __shfl_up(x, off, 64);
      if (lane >= off) x += y;
    }
    if (lane == 63) wsum[w] = x;
    __syncthreads();
    if (t < 16) {
      int s = wsum[t];
#pragma unroll
      for (int off = 1; off < 16; off <<= 1) {
        int y = __shfl_up(s, off, 64);
        if (t >= off) s += y;
      }
      wsum[t] = s;
    }
    __syncthreads();
    int woff = (w > 0) ? wsum[w - 1] : 0;
    int incl = x + woff;
    int carry = carry_s;
    if (i < n) rowstart[i] = carry + incl - v;
    __syncthreads();
    if (t == 1023) carry_s = carry + wsum[15];
    __syncthreads();
  }
  if (threadIdx.x == 0) rowstart[n] = carry_s;
}

__global__ void scatter2(const int* __restrict__ ei, int E,
                         const int* __restrict__ rowstart, const int* __restrict__ rank,
                         int* __restrict__ adj) {
  int e = blockIdx.x * blockDim.x + threadIdx.x;
  if (e >= E) return;
  int s = ei[e], d = ei[E + e];
  adj[rowstart[d] + rank[e]] = s;
}

// ---------------- fused weight packs: Wt0, Wt1 (MFMA frag layout), HW (fp32 head) ------
// Wt layout: Wt[k/8][col][k%8], zero-padded for k in [K, Kpad).
__global__ void pack_misc(const void* __restrict__ W0, const void* __restrict__ W1,
                          const void* __restrict__ Wn, const void* __restrict__ Wr,
                          const void* __restrict__ bn, const void* __restrict__ br,
                          const void* __restrict__ Wc, const void* __restrict__ bc,
                          ushort* __restrict__ Wt0, ushort* __restrict__ Wt1,
                          float* __restrict__ HW, int IN, int Kpad0,
                          const int* __restrict__ dtflag) {
  int dt = dtflag[0];
  int i = blockIdx.x * blockDim.x + threadIdx.x;
  int n0 = 128 * Kpad0;
  int n1 = n0 + 128 * 128;
  int s0 = IN * 128, s1 = s0 + 128 * 128, s2 = s1 + 128, s3 = s2 + 128, s4 = s3 + 256, s5 = s4 + 1;
  int n2 = n1 + s5;
  if (i < n0) {
    int c = i / Kpad0, k = i - c * Kpad0;
    float v = (k < IN) ? ldf(W0, (size_t)k * 128 + c, dt) : 0.f;
    Wt0[((size_t)(k >> 3) * 128 + c) * 8 + (k & 7)] = toBF(v);
  } else if (i < n1) {
    int j = i - n0;
    int c = j >> 7, k = j & 127;
    float v = ldf(W1, (size_t)k * 128 + c, dt);
    Wt1[((size_t)(k >> 3) * 128 + c) * 8 + (k & 7)] = toBF(v);
  } else if (i < n2) {
    int j = i - n1;
    float v;
    if (j < s0) v = ldf(Wn, j, dt);
    else if (j < s1) v = ldf(Wr, j - s0, dt);
    else if (j < s2) v = ldf(bn, j - s1, dt);
    else if (j < s3) v = ldf(br, j - s2, dt);
    else if (j < s4) v = ldf(Wc, j - s3, dt);
    else v = ldf(bc, 0, dt);
    HW[j] = v;
  }
}

// ---------------- MFMA GEMM v4: register-batched LDS panel stage, W from L2 -----------
// C[nrows,128] = A[nrows,K] @ W[K,128], A bf16 row-major, row stride RB=K*2 bytes.
// Full blocks: all panel chunks loaded to registers first (one latency exposure),
// then written to LDS. One barrier total; K-loop reads A-frags from LDS, W direct.
template <int RB, bool ALIGN16>
__global__ __launch_bounds__(256) void mfma_gemm4(const void* __restrict__ A0, const void* __restrict__ A1,
                                                  const ushort* __restrict__ Wt2,
                                                  bf16* __restrict__ C,
                                                  float2* __restrict__ as2, float2* __restrict__ ad2,
                                                  const void* __restrict__ aS, const void* __restrict__ aD,
                                                  int nrows, int K, const int* __restrict__ dtflag) {
  constexpr int PB = 64 * RB;                 // panel bytes (RB%4==0 -> PB%16==0)
  constexpr int NCHUNK = PB / 16;
  constexpr int NPT = (NCHUNK + 255) / 256;
  __shared__ __align__(16) unsigned char panel[PB + 64];  // +64 zeroed pad for K-tail reads
  int dtg = dtflag[0];
  const unsigned char* A = (const unsigned char*)((dtg && A1) ? A1 : A0);
  int tid = threadIdx.x;
  int row0 = blockIdx.x * 64;
  size_t gbase = (size_t)row0 * RB;

  if (row0 + 64 <= nrows) {
    const uint4* gsrc = (const uint4*)(A + gbase);
    uint4 st[NPT];
#pragma unroll
    for (int i = 0; i < NPT; i++) {
      int c = tid + i * 256;
      st[i] = (c < NCHUNK) ? gsrc[c] : (uint4){0u, 0u, 0u, 0u};
    }
#pragma unroll
    for (int i = 0; i < NPT; i++) {
      int c = tid + i * 256;
      if (c < NCHUNK) *(uint4*)&panel[(size_t)c << 4] = st[i];
    }
  } else {
    // partial last block: dword loop with bounds (avail is a multiple of 4)
    size_t avail = (size_t)nrows * RB - gbase;
    for (int b = tid * 4; b < PB; b += 1024) {
      uint v = ((size_t)(b + 4) <= avail) ? *(const uint*)(A + gbase + b) : 0u;
      *(uint*)&panel[b] = v;
    }
  }
  if (tid < 16) *(uint*)&panel[PB + tid * 4] = 0u;
  __syncthreads();

  int wave = tid >> 6, lane = tid & 63;
  int m = lane & 15, q = lane >> 4;
  int lrow = wave * 16 + m;
  const unsigned char* prow = &panel[(size_t)lrow * RB];

  f32x4 acc[8];
#pragma unroll
  for (int ct = 0; ct < 8; ct++) acc[ct] = (f32x4){0.f, 0.f, 0.f, 0.f};

  const ushort* wq = Wt2 + (size_t)q * 1024 + (size_t)m * 8;
  int niter = (K + 31) >> 5;
  for (int it = 0; it < niter; it++) {
    bf16x8 av;
    if (ALIGN16) {
      av = *(const bf16x8*)(prow + it * 64 + q * 16);
    } else {
      uint u[4];
#pragma unroll
      for (int j = 0; j < 4; j++) u[j] = *(const uint*)(prow + it * 64 + q * 16 + j * 4);
      __builtin_memcpy(&av, u, 16);
    }
    const ushort* wk = wq + (size_t)it * 4096;
    bf16x8 wv[8];
#pragma unroll
    for (int ct = 0; ct < 8; ct++) wv[ct] = *(const bf16x8*)(wk + ct * 128);
#pragma unroll
    for (int ct = 0; ct < 8; ct++)
      acc[ct] = __builtin_amdgcn_mfma_f32_16x16x32_bf16(av, wv[ct], acc[ct], 0, 0, 0);
  }

  // ---- C writeback (C/D: col=lane&15, row=q*4+r) ----
#pragma unroll
  for (int ct = 0; ct < 8; ct++) {
#pragma unroll
    for (int r = 0; r < 4; r++) {
      int grow = row0 + wave * 16 + q * 4 + r;
      if (grow < nrows) C[(size_t)grow * 128 + ct * 16 + m] = __float2bfloat16(acc[ct][r]);
    }
  }

  // ---- fused attention logits ----
  float aSv[8], aDv[8];
#pragma unroll
  for (int ct = 0; ct < 8; ct++) {
    aSv[ct] = ldf(aS, ct * 16 + m, dtg);
    aDv[ct] = ldf(aD, ct * 16 + m, dtg);
  }
#pragma unroll
  for (int r = 0; r < 4; r++) {
    float s0 = 0.f, s1 = 0.f, d0 = 0.f, d1 = 0.f;
#pragma unroll
    for (int ct = 0; ct < 4; ct++) {
      float v = acc[ct][r];
      s0 += v * aSv[ct]; d0 += v * aDv[ct];
    }
#pragma unroll
    for (int ct = 4; ct < 8; ct++) {
      float v = acc[ct][r];
      s1 += v * aSv[ct]; d1 += v * aDv[ct];
    }
#pragma unroll
    for (int off = 1; off < 16; off <<= 1) {
      s0 += __shfl_xor(s0, off, 64);
      s1 += __shfl_xor(s1, off, 64);
      d0 += __shfl_xor(d0, off, 64);
      d1 += __shfl_xor(d1, off, 64);
    }
    int grow = row0 + wave * 16 + q * 4 + r;
    if (m == 0 && grow < nrows) {
      as2[grow] = make_float2(s0, s1);
      ad2[grow] = make_float2(d0, d1);
    }
  }
}

// ---------------- generic fallback GEMM (any K / dtype) ----------------
__global__ __launch_bounds__(256) void mfma_gemm_gen(const void* __restrict__ A, const ushort* __restrict__ Wt2,
                                                     bf16* __restrict__ C,
                                                     float2* __restrict__ as2, float2* __restrict__ ad2,
                                                     const void* __restrict__ aS, const void* __restrict__ aD,
                                                     int nrows, int K, const int* __restrict__ dtflag) {
  int dtg = dtflag[0];
  int tid = threadIdx.x;
  int wave = tid >> 6, lane = tid & 63;
  int m = lane & 15, q = lane >> 4;
  int row0 = blockIdx.x * 64;
  int rowA = row0 + wave * 16 + m;
  int rA = rowA < nrows ? rowA : nrows - 1;

  f32x4 acc[8];
#pragma unroll
  for (int ct = 0; ct < 8; ct++) acc[ct] = (f32x4){0.f, 0.f, 0.f, 0.f};

  const ushort* wq = Wt2 + (size_t)q * 1024 + (size_t)m * 8;
  int niter = (K + 31) >> 5;
  for (int it = 0; it < niter; it++) {
    ushort u[8];
#pragma unroll
    for (int j = 0; j < 8; j++) {
      int k = it * 32 + q * 8 + j;
      u[j] = (k < K) ? toBF(ldf(A, (size_t)rA * K + k, dtg)) : (ushort)0;
    }
    bf16x8 av;
    __builtin_memcpy(&av, u, 16);
    const ushort* wk = wq + (size_t)it * 4096;
    bf16x8 wv[8];
#pragma unroll
    for (int ct = 0; ct < 8; ct++) wv[ct] = *(const bf16x8*)(wk + ct * 128);
#pragma unroll
    for (int ct = 0; ct < 8; ct++)
      acc[ct] = __builtin_amdgcn_mfma_f32_16x16x32_bf16(av, wv[ct], acc[ct], 0, 0, 0);
  }
#pragma unroll
  for (int ct = 0; ct < 8; ct++) {
#pragma unroll
    for (int r = 0; r < 4; r++) {
      int grow = row0 + wave * 16 + q * 4 + r;
      if (grow < nrows) C[(size_t)grow * 128 + ct * 16 + m] = __float2bfloat16(acc[ct][r]);
    }
  }
  float aSv[8], aDv[8];
#pragma unroll
  for (int ct = 0; ct < 8; ct++) {
    aSv[ct] = ldf(aS, ct * 16 + m, dtg);
    aDv[ct] = ldf(aD, ct * 16 + m, dtg);
  }
#pragma unroll
  for (int r = 0; r < 4; r++) {
    float s0 = 0.f, s1 = 0.f, d0 = 0.f, d1 = 0.f;
#pragma unroll
    for (int ct = 0; ct < 4; ct++) { float v = acc[ct][r]; s0 += v * aSv[ct]; d0 += v * aDv[ct]; }
#pragma unroll
    for (int ct = 4; ct < 8; ct++) { float v = acc[ct][r]; s1 += v * aSv[ct]; d1 += v * aDv[ct]; }
#pragma unroll
    for (int off = 1; off < 16; off <<= 1) {
      s0 += __shfl_xor(s0, off, 64);
      s1 += __shfl_xor(s1, off, 64);
      d0 += __shfl_xor(d0, off, 64);
      d1 += __shfl_xor(d1, off, 64);
    }
    int grow = row0 + wave * 16 + q * 4 + r;
    if (m == 0 && grow < nrows) {
      as2[grow] = make_float2(s0, s1);
      ad2[grow] = make_float2(d0, d1);
    }
  }
}

// ---------------- GAT aggregate v4: per-head LDS weights, analytic self-loop -----------
#define GCAP 64
__global__ __launch_bounds__(256) void gat_agg4(const bf16* __restrict__ xw,
                                                const float2* __restrict__ as2, const float2* __restrict__ ad2,
                                                const int* __restrict__ rowstart, const int* __restrict__ adj,
                                                const void* __restrict__ bias, bf16* __restrict__ out, int N,
                                                const int* __restrict__ dtflag) {
  __shared__ float sWh[4][2][GCAP];
  __shared__ int sS[4][GCAP];
  int dt = dtflag[0];
  int wslot = threadIdx.x >> 6;
  int lane = threadIdx.x & 63;
  int head = lane >> 5;
  int n = (blockIdx.x * blockDim.x + threadIdx.x) >> 6;
  bool act = n < N;
  int r0 = 0, r1 = 0;
  float2 adv = make_float2(0.f, 0.f), asn = make_float2(0.f, 0.f);
  if (act) { r0 = rowstart[n]; r1 = rowstart[n + 1]; adv = ad2[n]; asn = as2[n]; }
  int deg = r1 - r0;

  float es0 = asn.x + adv.x; es0 = es0 > 0.f ? es0 : 0.2f * es0;
  float es1 = asn.y + adv.y; es1 = es1 > 0.f ? es1 : 0.2f * es1;
  float ws0 = __expf(fminf(es0, 60.f)), ws1 = __expf(fminf(es1, 60.f));

  float den0, den1;
  {
    bool v = act && lane < deg;
    int s = v ? adj[r0 + lane] : 0;
    float w0 = 0.f, w1 = 0.f;
    if (v) {
      float2 asv = as2[s];
      float e0 = asv.x + adv.x; e0 = e0 > 0.f ? e0 : 0.2f * e0;
      float e1 = asv.y + adv.y; e1 = e1 > 0.f ? e1 : 0.2f * e1;
      w0 = __expf(fminf(e0, 60.f)); w1 = __expf(fminf(e1, 60.f));
    }
    sWh[wslot][0][lane] = w0;
    sWh[wslot][1][lane] = w1;
    sS[wslot][lane] = s;
    den0 = w0; den1 = w1;
  }
  for (int i = r0 + GCAP + lane; i < r1; i += 64) {
    int s = adj[i];
    float2 asv = as2[s];
    float e0 = asv.x + adv.x; e0 = e0 > 0.f ? e0 : 0.2f * e0;
    float e1 = asv.y + adv.y; e1 = e1 > 0.f ? e1 : 0.2f * e1;
    den0 += __expf(fminf(e0, 60.f)); den1 += __expf(fminf(e1, 60.f));
  }
#pragma unroll
  for (int off = 32; off > 0; off >>= 1) {
    den0 += __shfl_xor(den0, off, 64);
    den1 += __shfl_xor(den1, off, 64);
  }
  den0 += ws0; den1 += ws1;
  float inv0 = 1.f / (den0 + 1e-16f), inv1 = 1.f / (den1 + 1e-16f);

  const uint* xw32 = (const uint*)xw;
  float wsS = (lane < 32) ? ws0 : ws1;
  uint pvs = act ? xw32[((size_t)n << 6) + lane] : 0;
  float a0 = wsS * __uint_as_float(pvs << 16);
  float a1 = wsS * __uint_as_float(pvs & 0xffff0000u);
  int cap = deg < GCAP ? deg : GCAP;
  const float* wrow = sWh[wslot][head];
#pragma unroll 4
  for (int i = 0; i < cap; i++) {
    float ws = wrow[i];
    int s = sS[wslot][i];
    uint pv = xw32[((size_t)s << 6) + lane];
    a0 += ws * __uint_as_float(pv << 16);
    a1 += ws * __uint_as_float(pv & 0xffff0000u);
  }
  for (int i = GCAP; i < deg; i++) {
    int s = adj[r0 + i];
    float2 asv = as2[s];
    float e0 = asv.x + adv.x; e0 = e0 > 0.f ? e0 : 0.2f * e0;
    float e1 = asv.y + adv.y; e1 = e1 > 0.f ? e1 : 0.2f * e1;
    float w0 = __expf(fminf(e0, 60.f)), w1 = __expf(fminf(e1, 60.f));
    uint pv = xw32[((size_t)s << 6) + lane];
    float ws = (lane < 32) ? w0 : w1;
    a0 += ws * __uint_as_float(pv << 16);
    a1 += ws * __uint_as_float(pv & 0xffff0000u);
  }
  if (act) {
    int c0 = 2 * lane;
    float invs = (lane < 32) ? inv0 : inv1;
    float o0 = a0 * invs + ldf(bias, c0, dt);
    float o1 = a1 * invs + ldf(bias, c0 + 1, dt);
    o0 = o0 > 0.f ? o0 : 0.f;
    o1 = o1 > 0.f ? o1 : 0.f;
    uint pk = (uint)toBF(o0) | ((uint)toBF(o1) << 16);
    ((uint*)out)[(size_t)n * 64 + lane] = pk;
  }
}

// ---------------- parallel mean-pool (unnormalized sums; contiguous batch) ----------------
__global__ __launch_bounds__(256) void pool_kernel(const bf16* __restrict__ h, const int* __restrict__ batch,
                                                   float* __restrict__ pooled, int N) {
  int n0 = blockIdx.x * 128;
  int nEnd = n0 + 128 < N ? n0 + 128 : N;
  int col = threadIdx.x & 127, half = threadIdx.x >> 7;
  float acc = 0.f;
  int cur = -1;
  for (int n = n0 + half; n < nEnd; n += 2) {
    int g = batch[n];
    if (g != cur) {
      if (cur >= 0) atomicAdd(&pooled[(size_t)cur * 128 + col], acc);
      acc = 0.f; cur = g;
    }
    acc += toF(h[(size_t)n * 128 + col]);
  }
  if (cur >= 0) atomicAdd(&pooled[(size_t)cur * 128 + col], acc);
}

// ---------------- head v4: fp32-packed weights, no per-load dtype branch ----------------
__global__ __launch_bounds__(512) void head4_kernel(
    const float* __restrict__ pooled, const void* __restrict__ x, const int* __restrict__ batch,
    const float* __restrict__ HW, void* __restrict__ out, int N, int IN,
    const int* __restrict__ dtflag) {
  const float* Wn_f = HW;
  const float* Wr_f = HW + (size_t)IN * 128;
  const float* bn_f = Wr_f + 128 * 128;
  const float* br_f = bn_f + 128;
  const float* Wc_f = br_f + 128;
  const float* bc_f = Wc_f + 256;
  int dt = dtflag[0];
  int b = blockIdx.x;
  int tid = threadIdx.x;
  int t = tid & 127, g = tid >> 7;
  __shared__ int sr0, sr1;
  __shared__ float xs[512];
  __shared__ float pl[128];
  __shared__ float pn[4][128];
  __shared__ float pg[4][128];
  __shared__ float red[128];
  if (tid == 0) {
    int lo = 0, hi = N;
    while (lo < hi) { int mid = (lo + hi) >> 1; if (batch[mid] < b) lo = mid + 1; else hi = mid; }
    sr0 = lo;
  }
  if (tid == 1) {
    int lo = 0, hi = N, b1 = b + 1;
    while (lo < hi) { int mid = (lo + hi) >> 1; if (batch[mid] < b1) lo = mid + 1; else hi = mid; }
    sr1 = lo;
  }
  __syncthreads();
  int r0 = sr0;
  float inv_cnt = 1.f / (float)(sr1 - r0);
  if (tid < 128) pl[tid] = pooled[(size_t)b * 128 + tid] * inv_cnt;
  if (dt) {
    const float* xf = (const float*)x + (size_t)r0 * IN;
    for (int k = tid; k < IN; k += 512) xs[k] = xf[k];
  } else {
    const bf16* xb = (const bf16*)x + (size_t)r0 * IN;
    for (int k = tid; k < IN; k += 512) xs[k] = toF(xb[k]);
  }
  __syncthreads();

  float n0 = 0.f, n1 = 0.f, n2 = 0.f, n3 = 0.f;
  {
    int k = g;
    for (; k + 12 < IN; k += 16) {
      n0 += xs[k]      * Wn_f[(size_t)k * 128 + t];
      n1 += xs[k + 4]  * Wn_f[(size_t)(k + 4) * 128 + t];
      n2 += xs[k + 8]  * Wn_f[(size_t)(k + 8) * 128 + t];
      n3 += xs[k + 12] * Wn_f[(size_t)(k + 12) * 128 + t];
    }
    for (; k < IN; k += 4) n0 += xs[k] * Wn_f[(size_t)k * 128 + t];
  }
  float g0 = 0.f, g1 = 0.f;
  {
    int k = g;
    for (; k + 4 < 128; k += 8) {
      g0 += pl[k]     * Wr_f[(size_t)k * 128 + t];
      g1 += pl[k + 4] * Wr_f[(size_t)(k + 4) * 128 + t];
    }
    for (; k < 128; k += 4) g0 += pl[k] * Wr_f[(size_t)k * 128 + t];
  }
  pn[g][t] = (n0 + n1) + (n2 + n3);
  pg[g][t] = g0 + g1;
  __syncthreads();
  if (tid < 128) {
    float nw = pn[0][t] + pn[1][t] + pn[2][t] + pn[3][t] + bn_f[t];
    nw = nw > 0.f ? nw : 0.f;
    float gg = pg[0][t] + pg[1][t] + pg[2][t] + pg[3][t] + br_f[t];
    gg = gg > 0.f ? gg : 0.f;
    red[t] = gg * Wc_f[t] + nw * Wc_f[128 + t];
  }
  __syncthreads();
  for (int s = 64; s > 0; s >>= 1) {
    if (tid < s) red[tid] += red[tid + s];
    __syncthreads();
  }
  if (tid == 0) {
    float z = red[0] + bc_f[0];
    float r = 1.f / (1.f + __expf(-z));
    if (dt) ((float*)out)[b] = r;
    else ((bf16*)out)[b] = __float2bfloat16(r);
  }
}

extern "C" void kernel_launch(void* const* d_in, const int* in_sizes, int n_in,
                              void* d_out, int out_size, void* d_ws, size_t ws_size,
                              hipStream_t stream) {
  const void* x   = d_in[0];
  const void* W0  = d_in[1];
  const void* aS0 = d_in[2];
  const void* aD0 = d_in[3];
  const void* b0  = d_in[4];
  const void* W1  = d_in[5];
  const void* aS1 = d_in[6];
  const void* aD1 = d_in[7];
  const void* b1  = d_in[8];
  const void* Wn  = d_in[9];
  const void* bn  = d_in[10];
  const void* Wr  = d_in[11];
  const void* br  = d_in[12];
  const void* Wc  = d_in[13];
  const void* bc  = d_in[14];
  const int* ei    = (const int*)d_in[15];
  const int* batch = (const int*)d_in[16];

  const int N = in_sizes[16];
  const int IN = in_sizes[0] / N;
  const int E = in_sizes[15] / 2;
  const int B = out_size;
  const int Kpad0 = (IN + 31) / 32 * 32;   // 320
  const int hw_elems = IN * 128 + 128 * 128 + 128 + 128 + 256 + 1;
  const int misc_elems = 128 * Kpad0 + 128 * 128 + hw_elems;

  char* w = (char*)d_ws;
  size_t off = 0;
  auto alloc = [&](size_t bytes) { void* p = w + off; off += (bytes + 255) / 256 * 256; return p; };
  int* flag      = (int*)alloc(256);
  bf16* bufA     = (bf16*)alloc((size_t)N * 128 * 2);
  bf16* bufB     = (bf16*)alloc((size_t)N * 128 * 2);
  float2* as2    = (float2*)alloc((size_t)N * 8);
  float2* ad2    = (float2*)alloc((size_t)N * 8);
  int* cnt       = (int*)alloc((size_t)N * 4);
  int* rowstart  = (int*)alloc((size_t)(N + 1) * 4);
  int* rank      = (int*)alloc((size_t)E * 4);
  int* adj       = (int*)alloc((size_t)E * 4);
  ushort* Wt0    = (ushort*)alloc((size_t)128 * Kpad0 * 2);
  ushort* Wt1    = (ushort*)alloc((size_t)128 * 128 * 2);
  float* pooled  = (float*)alloc((size_t)B * 128 * 4);
  float* HW      = (float*)alloc((size_t)hw_elems * 4);
  ushort* xp     = (ushort*)alloc((size_t)N * IN * 2);   // bf16 repack of x (dt=1 only)

  int ndet = in_sizes[0] < 4096 ? in_sizes[0] : 4096;
  detect_dtype<<<1, 256, 0, stream>>>(x, ndet, flag);

  hipMemsetAsync(cnt, 0, sizeof(int) * N, stream);
  hipMemsetAsync(pooled, 0, sizeof(float) * (size_t)B * 128, stream);

  const int tb = 256;
  count_rank<<<(E + tb - 1) / tb, tb, 0, stream>>>(ei, E, cnt, rank);
  scan1<<<1, 1024, 0, stream>>>(cnt, rowstart, N);
  scatter2<<<(E + tb - 1) / tb, tb, 0, stream>>>(ei, E, rowstart, rank, adj);

  pack_misc<<<(misc_elems + 255) / 256, 256, 0, stream>>>(W0, W1, Wn, Wr, bn, br, Wc, bc,
                                                          Wt0, Wt1, HW, IN, Kpad0, flag);
  pack_xp<<<2048, 256, 0, stream>>>(x, xp, (size_t)N * IN, flag);

  int ggrid = (N + 63) / 64;
  int pgrid = (N + 127) / 128;
  int wgrid = ((N * 64) + 255) / 256;

  // Layer 0: fast panel path for the known shape (IN=310); generic fallback otherwise
  if (IN == 310) {
    mfma_gemm4<620, false><<<ggrid, 256, 0, stream>>>(x, xp, Wt0, bufA, as2, ad2, aS0, aD0, N, IN, flag);
  } else {
    mfma_gemm_gen<<<ggrid, 256, 0, stream>>>(x, Wt0, bufA, as2, ad2, aS0, aD0, N, IN, flag);
  }
  gat_agg4<<<wgrid, 256, 0, stream>>>(bufA, as2, ad2, rowstart, adj, b0, bufB, N, flag);

  // Layer 1: bf16 buffer, 256B rows, 16B-aligned
  mfma_gemm4<256, true><<<ggrid, 256, 0, stream>>>(bufB, nullptr, Wt1, bufA, as2, ad2, aS1, aD1, N, 128, flag);
  gat_agg4<<<wgrid, 256, 0, stream>>>(bufA, as2, ad2, rowstart, adj, b1, bufB, N, flag);

  // Head
  pool_kernel<<<pgrid, 256, 0, stream>>>(bufB, batch, pooled, N);
  head4_kernel<<<B, 512, 0, stream>>>(pooled, x, batch, HW, (void*)d_out, N, IN, flag);
}

// Round 11
// 358.531 us; speedup vs baseline: 1.0987x; 1.0987x over previous
//
#include <hip/hip_runtime.h>
#include <hip/hip_bf16.h>

typedef __hip_bfloat16 bf16;
typedef __attribute__((ext_vector_type(8))) __bf16 bf16x8;
typedef __attribute__((ext_vector_type(4))) float f32x4;

__device__ __forceinline__ float toF(bf16 v) { return __bfloat162float(v); }

// dual-dtype load: dt=1 -> underlying memory is fp32; dt=0 -> bf16
__device__ __forceinline__ float ldf(const void* p, size_t i, int dt) {
  return dt ? ((const float*)p)[i] : __bfloat162float(((const bf16*)p)[i]);
}
__device__ __forceinline__ ushort toBF(float f) {
  union { bf16 b; ushort u; } cv; cv.b = __float2bfloat16(f); return cv.u;
}

// ---------------- dtype detection ----------------
__global__ void detect_dtype(const void* x, int n, int* flag) {
  __shared__ int s;
  if (threadIdx.x == 0) s = 0;
  __syncthreads();
  const bf16* xb = (const bf16*)x;
  int bad = 0;
  for (int i = threadIdx.x; i < n; i += 256) {
    float v = __bfloat162float(xb[i]);
    if (!(fabsf(v) < 1e6f)) bad = 1;
  }
  if (bad) atomicOr(&s, 1);
  __syncthreads();
  if (threadIdx.x == 0) flag[0] = s;
}

// ---------------- optional x -> bf16 repack (only runs when dt==1) ----------------
__global__ void pack_xp(const void* __restrict__ x, ushort* __restrict__ xp, size_t total,
                        const int* __restrict__ dtflag) {
  if (dtflag[0] == 0) return;
  const float* xf = (const float*)x;
  size_t stride = (size_t)gridDim.x * blockDim.x;
  for (size_t i = blockIdx.x * (size_t)blockDim.x + threadIdx.x; i < total; i += stride)
    xp[i] = toBF(xf[i]);
}

// ---------------- CSR build (real edges only; self-loops analytic in agg) -------------
__global__ void count_rank(const int* __restrict__ ei, int E,
                           int* __restrict__ cnt, int* __restrict__ rank) {
  int e = blockIdx.x * blockDim.x + threadIdx.x;
  if (e >= E) return;
  int d = ei[E + e];
  rank[e] = atomicAdd(&cnt[d], 1);
}

// 3-phase scan (parallel): reduce -> top -> downsweep
__global__ __launch_bounds__(256) void scan_reduce(const int* __restrict__ cnt, int n, int* __restrict__ csum) {
  int base = blockIdx.x * 1024;
  int t = threadIdx.x;
  int s = 0;
#pragma unroll
  for (int j = 0; j < 4; j++) {
    int i = base + t * 4 + j;
    if (i < n) s += cnt[i];
  }
#pragma unroll
  for (int off = 32; off > 0; off >>= 1) s += __shfl_down(s, off, 64);
  __shared__ int ws[4];
  if ((t & 63) == 0) ws[t >> 6] = s;
  __syncthreads();
  if (t == 0) csum[blockIdx.x] = ws[0] + ws[1] + ws[2] + ws[3];
}

__global__ __launch_bounds__(256) void scan_top(int* __restrict__ csum, int nb, int* __restrict__ rowstart, int n) {
  __shared__ int sc[256];
  int t = threadIdx.x;
  int v0 = (t < nb) ? csum[t] : 0;
  sc[t] = v0;
  for (int off = 1; off < 256; off <<= 1) {
    __syncthreads();
    int v = (t >= off) ? sc[t - off] : 0;
    __syncthreads();
    sc[t] += v;
  }
  __syncthreads();
  if (t < nb) csum[t] = sc[t] - v0;  // exclusive
  if (t == 0) rowstart[n] = sc[255]; // total
}

__global__ __launch_bounds__(256) void scan_down(const int* __restrict__ cnt, int n,
                                                 const int* __restrict__ csum,
                                                 int* __restrict__ rowstart) {
  int base = blockIdx.x * 1024;
  int t = threadIdx.x, lane = t & 63, w = t >> 6;
  int v[4];
#pragma unroll
  for (int j = 0; j < 4; j++) {
    int i = base + t * 4 + j;
    v[j] = (i < n) ? cnt[i] : 0;
  }
  int s1 = v[0], s2 = s1 + v[1], s3 = s2 + v[2], s4 = s3 + v[3];
  int x = s4;
#pragma unroll
  for (int off = 1; off < 64; off <<= 1) {
    int y = __shfl_up(x, off, 64);
    if (lane >= off) x += y;
  }
  int texcl = x - s4;
  __shared__ int ws[4];
  if (lane == 63) ws[w] = x;
  __syncthreads();
  int woff = 0;
  for (int i = 0; i < 4; i++) if (i < w) woff += ws[i];
  int b0 = csum[blockIdx.x] + woff + texcl;
  int e0 = b0, e1 = b0 + s1, e2 = b0 + s2, e3 = b0 + s3;
  int i0 = base + t * 4;
  if (i0 + 0 < n) rowstart[i0 + 0] = e0;
  if (i0 + 1 < n) rowstart[i0 + 1] = e1;
  if (i0 + 2 < n) rowstart[i0 + 2] = e2;
  if (i0 + 3 < n) rowstart[i0 + 3] = e3;
}

__global__ void scatter2(const int* __restrict__ ei, int E,
                         const int* __restrict__ rowstart, const int* __restrict__ rank,
                         int* __restrict__ adj) {
  int e = blockIdx.x * blockDim.x + threadIdx.x;
  if (e >= E) return;
  int s = ei[e], d = ei[E + e];
  adj[rowstart[d] + rank[e]] = s;
}

// ---------------- fused weight packs: Wt0, Wt1 (MFMA frag layout), HW (fp32 head) ------
// Wt layout: Wt[k/8][col][k%8], zero-padded for k in [K, Kpad).
__global__ void pack_misc(const void* __restrict__ W0, const void* __restrict__ W1,
                          const void* __restrict__ Wn, const void* __restrict__ Wr,
                          const void* __restrict__ bn, const void* __restrict__ br,
                          const void* __restrict__ Wc, const void* __restrict__ bc,
                          ushort* __restrict__ Wt0, ushort* __restrict__ Wt1,
                          float* __restrict__ HW, int IN, int Kpad0,
                          const int* __restrict__ dtflag) {
  int dt = dtflag[0];
  int i = blockIdx.x * blockDim.x + threadIdx.x;
  int n0 = 128 * Kpad0;
  int n1 = n0 + 128 * 128;
  int s0 = IN * 128, s1 = s0 + 128 * 128, s2 = s1 + 128, s3 = s2 + 128, s4 = s3 + 256, s5 = s4 + 1;
  int n2 = n1 + s5;
  if (i < n0) {
    int c = i / Kpad0, k = i - c * Kpad0;
    float v = (k < IN) ? ldf(W0, (size_t)k * 128 + c, dt) : 0.f;
    Wt0[((size_t)(k >> 3) * 128 + c) * 8 + (k & 7)] = toBF(v);
  } else if (i < n1) {
    int j = i - n0;
    int c = j >> 7, k = j & 127;
    float v = ldf(W1, (size_t)k * 128 + c, dt);
    Wt1[((size_t)(k >> 3) * 128 + c) * 8 + (k & 7)] = toBF(v);
  } else if (i < n2) {
    int j = i - n1;
    float v;
    if (j < s0) v = ldf(Wn, j, dt);
    else if (j < s1) v = ldf(Wr, j - s0, dt);
    else if (j < s2) v = ldf(bn, j - s1, dt);
    else if (j < s3) v = ldf(br, j - s2, dt);
    else if (j < s4) v = ldf(Wc, j - s3, dt);
    else v = ldf(bc, 0, dt);
    HW[j] = v;
  }
}

// ---------------- MFMA GEMM v4: register-batched LDS panel stage, W from L2 -----------
template <int RB, bool ALIGN16>
__global__ __launch_bounds__(256) void mfma_gemm4(const void* __restrict__ A0, const void* __restrict__ A1,
                                                  const ushort* __restrict__ Wt2,
                                                  bf16* __restrict__ C,
                                                  float2* __restrict__ as2, float2* __restrict__ ad2,
                                                  const void* __restrict__ aS, const void* __restrict__ aD,
                                                  int nrows, int K, const int* __restrict__ dtflag) {
  constexpr int PB = 64 * RB;
  constexpr int NCHUNK = PB / 16;
  constexpr int NPT = (NCHUNK + 255) / 256;
  __shared__ __align__(16) unsigned char panel[PB + 64];
  int dtg = dtflag[0];
  const unsigned char* A = (const unsigned char*)((dtg && A1) ? A1 : A0);
  int tid = threadIdx.x;
  int row0 = blockIdx.x * 64;
  size_t gbase = (size_t)row0 * RB;

  if (row0 + 64 <= nrows) {
    const uint4* gsrc = (const uint4*)(A + gbase);
    uint4 st[NPT];
#pragma unroll
    for (int i = 0; i < NPT; i++) {
      int c = tid + i * 256;
      st[i] = (c < NCHUNK) ? gsrc[c] : (uint4){0u, 0u, 0u, 0u};
    }
#pragma unroll
    for (int i = 0; i < NPT; i++) {
      int c = tid + i * 256;
      if (c < NCHUNK) *(uint4*)&panel[(size_t)c << 4] = st[i];
    }
  } else {
    size_t avail = (size_t)nrows * RB - gbase;
    for (int b = tid * 4; b < PB; b += 1024) {
      uint v = ((size_t)(b + 4) <= avail) ? *(const uint*)(A + gbase + b) : 0u;
      *(uint*)&panel[b] = v;
    }
  }
  if (tid < 16) *(uint*)&panel[PB + tid * 4] = 0u;
  __syncthreads();

  int wave = tid >> 6, lane = tid & 63;
  int m = lane & 15, q = lane >> 4;
  int lrow = wave * 16 + m;
  const unsigned char* prow = &panel[(size_t)lrow * RB];

  f32x4 acc[8];
#pragma unroll
  for (int ct = 0; ct < 8; ct++) acc[ct] = (f32x4){0.f, 0.f, 0.f, 0.f};

  const ushort* wq = Wt2 + (size_t)q * 1024 + (size_t)m * 8;
  int niter = (K + 31) >> 5;
  for (int it = 0; it < niter; it++) {
    bf16x8 av;
    if (ALIGN16) {
      av = *(const bf16x8*)(prow + it * 64 + q * 16);
    } else {
      uint u[4];
#pragma unroll
      for (int j = 0; j < 4; j++) u[j] = *(const uint*)(prow + it * 64 + q * 16 + j * 4);
      __builtin_memcpy(&av, u, 16);
    }
    const ushort* wk = wq + (size_t)it * 4096;
    bf16x8 wv[8];
#pragma unroll
    for (int ct = 0; ct < 8; ct++) wv[ct] = *(const bf16x8*)(wk + ct * 128);
#pragma unroll
    for (int ct = 0; ct < 8; ct++)
      acc[ct] = __builtin_amdgcn_mfma_f32_16x16x32_bf16(av, wv[ct], acc[ct], 0, 0, 0);
  }

#pragma unroll
  for (int ct = 0; ct < 8; ct++) {
#pragma unroll
    for (int r = 0; r < 4; r++) {
      int grow = row0 + wave * 16 + q * 4 + r;
      if (grow < nrows) C[(size_t)grow * 128 + ct * 16 + m] = __float2bfloat16(acc[ct][r]);
    }
  }

  float aSv[8], aDv[8];
#pragma unroll
  for (int ct = 0; ct < 8; ct++) {
    aSv[ct] = ldf(aS, ct * 16 + m, dtg);
    aDv[ct] = ldf(aD, ct * 16 + m, dtg);
  }
#pragma unroll
  for (int r = 0; r < 4; r++) {
    float s0 = 0.f, s1 = 0.f, d0 = 0.f, d1 = 0.f;
#pragma unroll
    for (int ct = 0; ct < 4; ct++) {
      float v = acc[ct][r];
      s0 += v * aSv[ct]; d0 += v * aDv[ct];
    }
#pragma unroll
    for (int ct = 4; ct < 8; ct++) {
      float v = acc[ct][r];
      s1 += v * aSv[ct]; d1 += v * aDv[ct];
    }
#pragma unroll
    for (int off = 1; off < 16; off <<= 1) {
      s0 += __shfl_xor(s0, off, 64);
      s1 += __shfl_xor(s1, off, 64);
      d0 += __shfl_xor(d0, off, 64);
      d1 += __shfl_xor(d1, off, 64);
    }
    int grow = row0 + wave * 16 + q * 4 + r;
    if (m == 0 && grow < nrows) {
      as2[grow] = make_float2(s0, s1);
      ad2[grow] = make_float2(d0, d1);
    }
  }
}

// ---------------- generic fallback GEMM (any K / dtype) ----------------
__global__ __launch_bounds__(256) void mfma_gemm_gen(const void* __restrict__ A, const ushort* __restrict__ Wt2,
                                                     bf16* __restrict__ C,
                                                     float2* __restrict__ as2, float2* __restrict__ ad2,
                                                     const void* __restrict__ aS, const void* __restrict__ aD,
                                                     int nrows, int K, const int* __restrict__ dtflag) {
  int dtg = dtflag[0];
  int tid = threadIdx.x;
  int wave = tid >> 6, lane = tid & 63;
  int m = lane & 15, q = lane >> 4;
  int row0 = blockIdx.x * 64;
  int rowA = row0 + wave * 16 + m;
  int rA = rowA < nrows ? rowA : nrows - 1;

  f32x4 acc[8];
#pragma unroll
  for (int ct = 0; ct < 8; ct++) acc[ct] = (f32x4){0.f, 0.f, 0.f, 0.f};

  const ushort* wq = Wt2 + (size_t)q * 1024 + (size_t)m * 8;
  int niter = (K + 31) >> 5;
  for (int it = 0; it < niter; it++) {
    ushort u[8];
#pragma unroll
    for (int j = 0; j < 8; j++) {
      int k = it * 32 + q * 8 + j;
      u[j] = (k < K) ? toBF(ldf(A, (size_t)rA * K + k, dtg)) : (ushort)0;
    }
    bf16x8 av;
    __builtin_memcpy(&av, u, 16);
    const ushort* wk = wq + (size_t)it * 4096;
    bf16x8 wv[8];
#pragma unroll
    for (int ct = 0; ct < 8; ct++) wv[ct] = *(const bf16x8*)(wk + ct * 128);
#pragma unroll
    for (int ct = 0; ct < 8; ct++)
      acc[ct] = __builtin_amdgcn_mfma_f32_16x16x32_bf16(av, wv[ct], acc[ct], 0, 0, 0);
  }
#pragma unroll
  for (int ct = 0; ct < 8; ct++) {
#pragma unroll
    for (int r = 0; r < 4; r++) {
      int grow = row0 + wave * 16 + q * 4 + r;
      if (grow < nrows) C[(size_t)grow * 128 + ct * 16 + m] = __float2bfloat16(acc[ct][r]);
    }
  }
  float aSv[8], aDv[8];
#pragma unroll
  for (int ct = 0; ct < 8; ct++) {
    aSv[ct] = ldf(aS, ct * 16 + m, dtg);
    aDv[ct] = ldf(aD, ct * 16 + m, dtg);
  }
#pragma unroll
  for (int r = 0; r < 4; r++) {
    float s0 = 0.f, s1 = 0.f, d0 = 0.f, d1 = 0.f;
#pragma unroll
    for (int ct = 0; ct < 4; ct++) { float v = acc[ct][r]; s0 += v * aSv[ct]; d0 += v * aDv[ct]; }
#pragma unroll
    for (int ct = 4; ct < 8; ct++) { float v = acc[ct][r]; s1 += v * aSv[ct]; d1 += v * aDv[ct]; }
#pragma unroll
    for (int off = 1; off < 16; off <<= 1) {
      s0 += __shfl_xor(s0, off, 64);
      s1 += __shfl_xor(s1, off, 64);
      d0 += __shfl_xor(d0, off, 64);
      d1 += __shfl_xor(d1, off, 64);
    }
    int grow = row0 + wave * 16 + q * 4 + r;
    if (m == 0 && grow < nrows) {
      as2[grow] = make_float2(s0, s1);
      ad2[grow] = make_float2(d0, d1);
    }
  }
}

// ---------------- GAT aggregate v4: per-head LDS weights, analytic self-loop -----------
#define GCAP 64
__global__ __launch_bounds__(256) void gat_agg4(const bf16* __restrict__ xw,
                                                const float2* __restrict__ as2, const float2* __restrict__ ad2,
                                                const int* __restrict__ rowstart, const int* __restrict__ adj,
                                                const void* __restrict__ bias, bf16* __restrict__ out, int N,
                                                const int* __restrict__ dtflag) {
  __shared__ float sWh[4][2][GCAP];
  __shared__ int sS[4][GCAP];
  int dt = dtflag[0];
  int wslot = threadIdx.x >> 6;
  int lane = threadIdx.x & 63;
  int head = lane >> 5;
  int n = (blockIdx.x * blockDim.x + threadIdx.x) >> 6;
  bool act = n < N;
  int r0 = 0, r1 = 0;
  float2 adv = make_float2(0.f, 0.f), asn = make_float2(0.f, 0.f);
  if (act) { r0 = rowstart[n]; r1 = rowstart[n + 1]; adv = ad2[n]; asn = as2[n]; }
  int deg = r1 - r0;

  float es0 = asn.x + adv.x; es0 = es0 > 0.f ? es0 : 0.2f * es0;
  float es1 = asn.y + adv.y; es1 = es1 > 0.f ? es1 : 0.2f * es1;
  float ws0 = __expf(fminf(es0, 60.f)), ws1 = __expf(fminf(es1, 60.f));

  float den0, den1;
  {
    bool v = act && lane < deg;
    int s = v ? adj[r0 + lane] : 0;
    float w0 = 0.f, w1 = 0.f;
    if (v) {
      float2 asv = as2[s];
      float e0 = asv.x + adv.x; e0 = e0 > 0.f ? e0 : 0.2f * e0;
      float e1 = asv.y + adv.y; e1 = e1 > 0.f ? e1 : 0.2f * e1;
      w0 = __expf(fminf(e0, 60.f)); w1 = __expf(fminf(e1, 60.f));
    }
    sWh[wslot][0][lane] = w0;
    sWh[wslot][1][lane] = w1;
    sS[wslot][lane] = s;
    den0 = w0; den1 = w1;
  }
  for (int i = r0 + GCAP + lane; i < r1; i += 64) {
    int s = adj[i];
    float2 asv = as2[s];
    float e0 = asv.x + adv.x; e0 = e0 > 0.f ? e0 : 0.2f * e0;
    float e1 = asv.y + adv.y; e1 = e1 > 0.f ? e1 : 0.2f * e1;
    den0 += __expf(fminf(e0, 60.f)); den1 += __expf(fminf(e1, 60.f));
  }
#pragma unroll
  for (int off = 32; off > 0; off >>= 1) {
    den0 += __shfl_xor(den0, off, 64);
    den1 += __shfl_xor(den1, off, 64);
  }
  den0 += ws0; den1 += ws1;
  float inv0 = 1.f / (den0 + 1e-16f), inv1 = 1.f / (den1 + 1e-16f);

  const uint* xw32 = (const uint*)xw;
  float wsS = (lane < 32) ? ws0 : ws1;
  uint pvs = act ? xw32[((size_t)n << 6) + lane] : 0;
  float a0 = wsS * __uint_as_float(pvs << 16);
  float a1 = wsS * __uint_as_float(pvs & 0xffff0000u);
  int cap = deg < GCAP ? deg : GCAP;
  const float* wrow = sWh[wslot][head];
#pragma unroll 4
  for (int i = 0; i < cap; i++) {
    float ws = wrow[i];
    int s = sS[wslot][i];
    uint pv = xw32[((size_t)s << 6) + lane];
    a0 += ws * __uint_as_float(pv << 16);
    a1 += ws * __uint_as_float(pv & 0xffff0000u);
  }
  for (int i = GCAP; i < deg; i++) {
    int s = adj[r0 + i];
    float2 asv = as2[s];
    float e0 = asv.x + adv.x; e0 = e0 > 0.f ? e0 : 0.2f * e0;
    float e1 = asv.y + adv.y; e1 = e1 > 0.f ? e1 : 0.2f * e1;
    float w0 = __expf(fminf(e0, 60.f)), w1 = __expf(fminf(e1, 60.f));
    uint pv = xw32[((size_t)s << 6) + lane];
    float ws = (lane < 32) ? w0 : w1;
    a0 += ws * __uint_as_float(pv << 16);
    a1 += ws * __uint_as_float(pv & 0xffff0000u);
  }
  if (act) {
    int c0 = 2 * lane;
    float invs = (lane < 32) ? inv0 : inv1;
    float o0 = a0 * invs + ldf(bias, c0, dt);
    float o1 = a1 * invs + ldf(bias, c0 + 1, dt);
    o0 = o0 > 0.f ? o0 : 0.f;
    o1 = o1 > 0.f ? o1 : 0.f;
    uint pk = (uint)toBF(o0) | ((uint)toBF(o1) << 16);
    ((uint*)out)[(size_t)n * 64 + lane] = pk;
  }
}

// ---------------- parallel mean-pool (unnormalized sums; contiguous batch) ----------------
__global__ __launch_bounds__(256) void pool_kernel(const bf16* __restrict__ h, const int* __restrict__ batch,
                                                   float* __restrict__ pooled, int N) {
  int n0 = blockIdx.x * 128;
  int nEnd = n0 + 128 < N ? n0 + 128 : N;
  int col = threadIdx.x & 127, half = threadIdx.x >> 7;
  float acc = 0.f;
  int cur = -1;
  for (int n = n0 + half; n < nEnd; n += 2) {
    int g = batch[n];
    if (g != cur) {
      if (cur >= 0) atomicAdd(&pooled[(size_t)cur * 128 + col], acc);
      acc = 0.f; cur = g;
    }
    acc += toF(h[(size_t)n * 128 + col]);
  }
  if (cur >= 0) atomicAdd(&pooled[(size_t)cur * 128 + col], acc);
}

// ---------------- head v4: fp32-packed weights, no per-load dtype branch ----------------
__global__ __launch_bounds__(512) void head4_kernel(
    const float* __restrict__ pooled, const void* __restrict__ x, const int* __restrict__ batch,
    const float* __restrict__ HW, void* __restrict__ out, int N, int IN,
    const int* __restrict__ dtflag) {
  const float* Wn_f = HW;
  const float* Wr_f = HW + (size_t)IN * 128;
  const float* bn_f = Wr_f + 128 * 128;
  const float* br_f = bn_f + 128;
  const float* Wc_f = br_f + 128;
  const float* bc_f = Wc_f + 256;
  int dt = dtflag[0];
  int b = blockIdx.x;
  int tid = threadIdx.x;
  int t = tid & 127, g = tid >> 7;
  __shared__ int sr0, sr1;
  __shared__ float xs[512];
  __shared__ float pl[128];
  __shared__ float pn[4][128];
  __shared__ float pg[4][128];
  __shared__ float red[128];
  if (tid == 0) {
    int lo = 0, hi = N;
    while (lo < hi) { int mid = (lo + hi) >> 1; if (batch[mid] < b) lo = mid + 1; else hi = mid; }
    sr0 = lo;
  }
  if (tid == 1) {
    int lo = 0, hi = N, b1 = b + 1;
    while (lo < hi) { int mid = (lo + hi) >> 1; if (batch[mid] < b1) lo = mid + 1; else hi = mid; }
    sr1 = lo;
  }
  __syncthreads();
  int r0 = sr0;
  float inv_cnt = 1.f / (float)(sr1 - r0);
  if (tid < 128) pl[tid] = pooled[(size_t)b * 128 + tid] * inv_cnt;
  if (dt) {
    const float* xf = (const float*)x + (size_t)r0 * IN;
    for (int k = tid; k < IN; k += 512) xs[k] = xf[k];
  } else {
    const bf16* xb = (const bf16*)x + (size_t)r0 * IN;
    for (int k = tid; k < IN; k += 512) xs[k] = toF(xb[k]);
  }
  __syncthreads();

  float n0 = 0.f, n1 = 0.f, n2 = 0.f, n3 = 0.f;
  {
    int k = g;
    for (; k + 12 < IN; k += 16) {
      n0 += xs[k]      * Wn_f[(size_t)k * 128 + t];
      n1 += xs[k + 4]  * Wn_f[(size_t)(k + 4) * 128 + t];
      n2 += xs[k + 8]  * Wn_f[(size_t)(k + 8) * 128 + t];
      n3 += xs[k + 12] * Wn_f[(size_t)(k + 12) * 128 + t];
    }
    for (; k < IN; k += 4) n0 += xs[k] * Wn_f[(size_t)k * 128 + t];
  }
  float g0 = 0.f, g1 = 0.f;
  {
    int k = g;
    for (; k + 4 < 128; k += 8) {
      g0 += pl[k]     * Wr_f[(size_t)k * 128 + t];
      g1 += pl[k + 4] * Wr_f[(size_t)(k + 4) * 128 + t];
    }
    for (; k < 128; k += 4) g0 += pl[k] * Wr_f[(size_t)k * 128 + t];
  }
  pn[g][t] = (n0 + n1) + (n2 + n3);
  pg[g][t] = g0 + g1;
  __syncthreads();
  if (tid < 128) {
    float nw = pn[0][t] + pn[1][t] + pn[2][t] + pn[3][t] + bn_f[t];
    nw = nw > 0.f ? nw : 0.f;
    float gg = pg[0][t] + pg[1][t] + pg[2][t] + pg[3][t] + br_f[t];
    gg = gg > 0.f ? gg : 0.f;
    red[t] = gg * Wc_f[t] + nw * Wc_f[128 + t];
  }
  __syncthreads();
  for (int s = 64; s > 0; s >>= 1) {
    if (tid < s) red[tid] += red[tid + s];
    __syncthreads();
  }
  if (tid == 0) {
    float z = red[0] + bc_f[0];
    float r = 1.f / (1.f + __expf(-z));
    if (dt) ((float*)out)[b] = r;
    else ((bf16*)out)[b] = __float2bfloat16(r);
  }
}

extern "C" void kernel_launch(void* const* d_in, const int* in_sizes, int n_in,
                              void* d_out, int out_size, void* d_ws, size_t ws_size,
                              hipStream_t stream) {
  const void* x   = d_in[0];
  const void* W0  = d_in[1];
  const void* aS0 = d_in[2];
  const void* aD0 = d_in[3];
  const void* b0  = d_in[4];
  const void* W1  = d_in[5];
  const void* aS1 = d_in[6];
  const void* aD1 = d_in[7];
  const void* b1  = d_in[8];
  const void* Wn  = d_in[9];
  const void* bn  = d_in[10];
  const void* Wr  = d_in[11];
  const void* br  = d_in[12];
  const void* Wc  = d_in[13];
  const void* bc  = d_in[14];
  const int* ei    = (const int*)d_in[15];
  const int* batch = (const int*)d_in[16];

  const int N = in_sizes[16];
  const int IN = in_sizes[0] / N;
  const int E = in_sizes[15] / 2;
  const int B = out_size;
  const int Kpad0 = (IN + 31) / 32 * 32;   // 320
  const int hw_elems = IN * 128 + 128 * 128 + 128 + 128 + 256 + 1;
  const int misc_elems = 128 * Kpad0 + 128 * 128 + hw_elems;

  char* w = (char*)d_ws;
  size_t off = 0;
  auto alloc = [&](size_t bytes) { void* p = w + off; off += (bytes + 255) / 256 * 256; return p; };
  int* flag      = (int*)alloc(256);
  bf16* bufA     = (bf16*)alloc((size_t)N * 128 * 2);
  bf16* bufB     = (bf16*)alloc((size_t)N * 128 * 2);
  float2* as2    = (float2*)alloc((size_t)N * 8);
  float2* ad2    = (float2*)alloc((size_t)N * 8);
  int* cnt       = (int*)alloc((size_t)N * 4);
  int* rowstart  = (int*)alloc((size_t)(N + 1) * 4);
  int* rank      = (int*)alloc((size_t)E * 4);
  int* adj       = (int*)alloc((size_t)E * 4);
  int* csum      = (int*)alloc(1024);
  ushort* Wt0    = (ushort*)alloc((size_t)128 * Kpad0 * 2);
  ushort* Wt1    = (ushort*)alloc((size_t)128 * 128 * 2);
  float* pooled  = (float*)alloc((size_t)B * 128 * 4);
  float* HW      = (float*)alloc((size_t)hw_elems * 4);
  ushort* xp     = (ushort*)alloc((size_t)N * IN * 2);   // bf16 repack of x (dt=1 only)

  int ndet = in_sizes[0] < 4096 ? in_sizes[0] : 4096;
  detect_dtype<<<1, 256, 0, stream>>>(x, ndet, flag);

  hipMemsetAsync(cnt, 0, sizeof(int) * N, stream);
  hipMemsetAsync(pooled, 0, sizeof(float) * (size_t)B * 128, stream);

  const int tb = 256;
  count_rank<<<(E + tb - 1) / tb, tb, 0, stream>>>(ei, E, cnt, rank);
  int nb = (N + 1023) / 1024;
  scan_reduce<<<nb, 256, 0, stream>>>(cnt, N, csum);
  scan_top<<<1, 256, 0, stream>>>(csum, nb, rowstart, N);
  scan_down<<<nb, 256, 0, stream>>>(cnt, N, csum, rowstart);
  scatter2<<<(E + tb - 1) / tb, tb, 0, stream>>>(ei, E, rowstart, rank, adj);

  pack_misc<<<(misc_elems + 255) / 256, 256, 0, stream>>>(W0, W1, Wn, Wr, bn, br, Wc, bc,
                                                          Wt0, Wt1, HW, IN, Kpad0, flag);
  pack_xp<<<2048, 256, 0, stream>>>(x, xp, (size_t)N * IN, flag);

  int ggrid = (N + 63) / 64;
  int pgrid = (N + 127) / 128;
  int wgrid = ((N * 64) + 255) / 256;

  // Layer 0: fast panel path for the known shape (IN=310); generic fallback otherwise
  if (IN == 310) {
    mfma_gemm4<620, false><<<ggrid, 256, 0, stream>>>(x, xp, Wt0, bufA, as2, ad2, aS0, aD0, N, IN, flag);
  } else {
    mfma_gemm_gen<<<ggrid, 256, 0, stream>>>(x, Wt0, bufA, as2, ad2, aS0, aD0, N, IN, flag);
  }
  gat_agg4<<<wgrid, 256, 0, stream>>>(bufA, as2, ad2, rowstart, adj, b0, bufB, N, flag);

  // Layer 1: bf16 buffer, 256B rows, 16B-aligned
  mfma_gemm4<256, true><<<ggrid, 256, 0, stream>>>(bufB, nullptr, Wt1, bufA, as2, ad2, aS1, aD1, N, 128, flag);
  gat_agg4<<<wgrid, 256, 0, stream>>>(bufA, as2, ad2, rowstart, adj, b1, bufB, N, flag);

  // Head
  pool_kernel<<<pgrid, 256, 0, stream>>>(bufB, batch, pooled, N);
  head4_kernel<<<B, 512, 0, stream>>>(pooled, x, batch, HW, (void*)d_out, N, IN, flag);
}